// Round 3
// baseline (156.639 us; speedup 1.0000x reference)
//
#include <hip/hip_runtime.h>
#include <hip/hip_bf16.h>

typedef float f32x4 __attribute__((ext_vector_type(4)));
typedef __bf16 bf16x8 __attribute__((ext_vector_type(8)));
typedef unsigned short ushort8 __attribute__((ext_vector_type(8)));

constexpr int kB = 2048;
constexpr int kF = 40;
constexpr int kD = 64;
constexpr int kP = 780;            // 40*39/2
constexpr int kFD = kF * kD;       // 2560
constexpr int BT = 512;            // batch rows per block
constexpr int NBT = kB / BT;       // 4
constexpr int NBLK = kP * NBT;     // 3120 blocks
constexpr int PASSES = BT / 64;    // 8 (4 waves x 16 rows each per pass)

// workspace layout
constexpr size_t X_BF_ELEMS = (size_t)kB * kFD;            // 5,242,880 bf16
constexpr size_t X_BF_BYTES = X_BF_ELEMS * 2;              // 10.49 MB
constexpr size_t W2_VEC_CNT = (size_t)kP * 512;            // bf16x8 vectors
constexpr size_t W2_BYTES   = W2_VEC_CNT * 16;             // 6.39 MB
constexpr size_t WS_NEEDED  = X_BF_BYTES + W2_BYTES;

constexpr int XCONV_BLOCKS = (int)(X_BF_ELEMS / 8 / 256);  // 2560
constexpr int PRE_BLOCKS = XCONV_BLOCKS + kP;              // 3340

__device__ __forceinline__ unsigned short f2bf_bits(float f) {
  unsigned u = __builtin_bit_cast(unsigned, f);
  u += 0x7FFFu + ((u >> 16) & 1u);
  return (unsigned short)(u >> 16);
}

// ---- pre-pass: convert x -> bf16 (row major) and W -> bf16 fragment-packed
// W2[p][frag=kk*4+nb][lane] as bf16x8, value[t] = W[p][kk*32+hi*8+t][nb*16+lo]
__global__ __launch_bounds__(256) void bilinear_prepass(
    const float* __restrict__ x, const float* __restrict__ W,
    unsigned short* __restrict__ x_bf, ushort8* __restrict__ W2) {
  const int blk = blockIdx.x;
  const int tid = threadIdx.x;
  if (blk < XCONV_BLOCKS) {
    const size_t i = ((size_t)blk * 256 + tid) * 8;
    f32x4 v0 = *(const f32x4*)(x + i);
    f32x4 v1 = *(const f32x4*)(x + i + 4);
    ushort8 o;
#pragma unroll
    for (int t = 0; t < 4; ++t) {
      o[t] = f2bf_bits(v0[t]);
      o[t + 4] = f2bf_bits(v1[t]);
    }
    *(ushort8*)(x_bf + i) = o;
  } else {
    const int p = blk - XCONV_BLOCKS;
    const float* wp = W + (size_t)p * (kD * kD);
#pragma unroll
    for (int rep = 0; rep < 2; ++rep) {
      const int v = tid + rep * 256;       // 512 vectors per p
      const int frag = v >> 6;             // kk*4+nb
      const int lane = v & 63;
      const int kk = frag >> 2, nb = frag & 3;
      const int lo = lane & 15, hi = lane >> 4;
      ushort8 o;
#pragma unroll
      for (int t = 0; t < 8; ++t)
        o[t] = f2bf_bits(wp[(kk * 32 + hi * 8 + t) * kD + nb * 16 + lo]);
      *(ushort8*)&W2[(size_t)p * 512 + v] = o;
    }
  }
}

// ---- main kernel: Y^T = mfma(W_frag, X_frag) so each lane owns one batch row
__global__ __launch_bounds__(256) void bilinear_main2(
    const float* __restrict__ x, const unsigned short* __restrict__ x_bf,
    const ushort8* __restrict__ W2, float* __restrict__ out) {
  // XCD swizzle: btile constant per XCD (x slice L2-resident), p streams.
  const int gid = blockIdx.x;
  const int xcd = gid & 7;
  const int g = gid >> 3;                  // [0, 390)
  const int btile = xcd >> 1;              // [0, 4)  fixed per XCD
  const int p = (xcd & 1) * (kP / 2) + g;  // [0, 780)

  // decode pair (i_f, j_f) from p (triu_indices order, k=1)
  int i_f = 0, s = 0;
  while (s + (kF - 1 - i_f) <= p) { s += kF - 1 - i_f; ++i_f; }
  const int j_f = i_f + 1 + (p - s);

  const int lane = threadIdx.x & 63;
  const int wave = threadIdx.x >> 6;
  const int lo = lane & 15;
  const int hi = lane >> 4;

  // W fragments: 8 coalesced 16B loads, reused over all 8 passes
  bf16x8 bfrag[2][4];
#pragma unroll
  for (int kk = 0; kk < 2; ++kk)
#pragma unroll
    for (int nb = 0; nb < 4; ++nb)
      bfrag[kk][nb] = __builtin_bit_cast(
          bf16x8, W2[(size_t)p * 512 + (kk * 4 + nb) * 64 + lane]);

  const int b0 = btile * BT;
  for (int pass = 0; pass < PASSES; ++pass) {
    const int rb = b0 + pass * 64 + wave * 16;
    const int row = rb + lo;               // one batch row per lane

    // A(X) fragments as B-operand: lane holds x[row][i_f*64 + kk*32 + hi*8 + t]
    const unsigned short* xi = x_bf + (size_t)row * kFD + i_f * kD;
    bf16x8 afrag0 = __builtin_bit_cast(bf16x8, *(const ushort8*)(xi + hi * 8));
    bf16x8 afrag1 = __builtin_bit_cast(bf16x8, *(const ushort8*)(xi + 32 + hi * 8));

    // acc[nb][q] = Y[row][nb*16 + hi*4 + q]
    f32x4 acc[4];
#pragma unroll
    for (int nb = 0; nb < 4; ++nb) acc[nb] = f32x4{0.f, 0.f, 0.f, 0.f};
#pragma unroll
    for (int nb = 0; nb < 4; ++nb)
      acc[nb] = __builtin_amdgcn_mfma_f32_16x16x32_bf16(bfrag[0][nb], afrag0,
                                                        acc[nb], 0, 0, 0);
#pragma unroll
    for (int nb = 0; nb < 4; ++nb)
      acc[nb] = __builtin_amdgcn_mfma_f32_16x16x32_bf16(bfrag[1][nb], afrag1,
                                                        acc[nb], 0, 0, 0);

    // epilogue: sum_e Y[row][e] * x[row][j_f*64+e], e = nb*16 + hi*4 + q
    const float* xj = x + (size_t)row * kFD + j_f * kD + hi * 4;
    float sum = 0.f;
#pragma unroll
    for (int nb = 0; nb < 4; ++nb) {
      f32x4 xv = *(const f32x4*)(xj + nb * 16);
#pragma unroll
      for (int q = 0; q < 4; ++q) sum = fmaf(acc[nb][q], xv[q], sum);
    }
    sum += __shfl_xor(sum, 16, 64);
    sum += __shfl_xor(sum, 32, 64);
    if (hi == 0) out[(size_t)row * kP + p] = sum;
  }
}

// ---- fallback (round-1 kernel) if workspace is too small ----
__global__ __launch_bounds__(256) void bilinear_fb(
    const float* __restrict__ x, const float* __restrict__ W,
    float* __restrict__ out) {
  const int gid = blockIdx.x;
  const int item = (gid & 7) * (NBLK / 8) + (gid >> 3);
  const int p = item >> 2;
  const int btile = item & 3;
  int i_f = 0, s = 0;
  while (s + (kF - 1 - i_f) <= p) { s += kF - 1 - i_f; ++i_f; }
  const int j_f = i_f + 1 + (p - s);
  const int lane = threadIdx.x & 63;
  const int wave = threadIdx.x >> 6;
  const int lo = lane & 15;
  const int hi = lane >> 4;
  const float* wp = W + (size_t)p * (kD * kD);
  bf16x8 bfrag[2][4];
#pragma unroll
  for (int kk = 0; kk < 2; ++kk)
#pragma unroll
    for (int nb = 0; nb < 4; ++nb) {
      ushort8 tmp;
#pragma unroll
      for (int t = 0; t < 8; ++t)
        tmp[t] = f2bf_bits(wp[(kk * 32 + hi * 8 + t) * kD + nb * 16 + lo]);
      bfrag[kk][nb] = __builtin_bit_cast(bf16x8, tmp);
    }
  const int b0 = btile * BT;
  for (int pass = 0; pass < PASSES; ++pass) {
    const int rb = b0 + pass * 64 + wave * 16;
    const float* xi = x + (size_t)(rb + lo) * kFD + i_f * kD;
    bf16x8 afrag[2];
#pragma unroll
    for (int kk = 0; kk < 2; ++kk) {
      f32x4 v0 = *(const f32x4*)(xi + kk * 32 + hi * 8);
      f32x4 v1 = *(const f32x4*)(xi + kk * 32 + hi * 8 + 4);
      ushort8 tmp;
#pragma unroll
      for (int t = 0; t < 4; ++t) {
        tmp[t] = f2bf_bits(v0[t]);
        tmp[t + 4] = f2bf_bits(v1[t]);
      }
      afrag[kk] = __builtin_bit_cast(bf16x8, tmp);
    }
    f32x4 acc[4];
#pragma unroll
    for (int nb = 0; nb < 4; ++nb) acc[nb] = f32x4{0.f, 0.f, 0.f, 0.f};
#pragma unroll
    for (int kk = 0; kk < 2; ++kk)
#pragma unroll
      for (int nb = 0; nb < 4; ++nb)
        acc[nb] = __builtin_amdgcn_mfma_f32_16x16x32_bf16(afrag[kk], bfrag[kk][nb],
                                                          acc[nb], 0, 0, 0);
#pragma unroll
    for (int q = 0; q < 4; ++q) {
      const int row = rb + hi * 4 + q;
      const float* xj = x + (size_t)row * kFD + j_f * kD + lo;
      float sum = 0.f;
#pragma unroll
      for (int nb = 0; nb < 4; ++nb) sum += acc[nb][q] * xj[nb * 16];
      sum += __shfl_xor(sum, 1, 64);
      sum += __shfl_xor(sum, 2, 64);
      sum += __shfl_xor(sum, 4, 64);
      sum += __shfl_xor(sum, 8, 64);
      if (lo == 0) out[(size_t)row * kP + p] = sum;
    }
  }
}

extern "C" void kernel_launch(void* const* d_in, const int* in_sizes, int n_in,
                              void* d_out, int out_size, void* d_ws, size_t ws_size,
                              hipStream_t stream) {
  const float* x = (const float*)d_in[0];
  const float* W = (const float*)d_in[1];
  float* out = (float*)d_out;
  if (ws_size >= WS_NEEDED) {
    unsigned short* x_bf = (unsigned short*)d_ws;
    ushort8* W2 = (ushort8*)((char*)d_ws + X_BF_BYTES);
    hipLaunchKernelGGL(bilinear_prepass, dim3(PRE_BLOCKS), dim3(256), 0, stream,
                       x, W, x_bf, W2);
    hipLaunchKernelGGL(bilinear_main2, dim3(NBLK), dim3(256), 0, stream,
                       x, x_bf, W2, out);
  } else {
    hipLaunchKernelGGL(bilinear_fb, dim3(NBLK), dim3(256), 0, stream, x, W, out);
  }
}

// Round 6
// 153.515 us; speedup vs baseline: 1.0203x; 1.0203x over previous
//
#include <hip/hip_runtime.h>
#include <hip/hip_bf16.h>

typedef float f32x4 __attribute__((ext_vector_type(4)));
typedef __bf16 bf16x8 __attribute__((ext_vector_type(8)));
typedef unsigned short ushort8 __attribute__((ext_vector_type(8)));
typedef unsigned short u16x4 __attribute__((ext_vector_type(4)));

constexpr int kB = 2048;
constexpr int kF = 40;
constexpr int kD = 64;
constexpr int kP = 780;            // 40*39/2
constexpr int kFD = kF * kD;       // 2560
constexpr int BT = 512;            // batch rows per block
constexpr int NBT = kB / BT;       // 4
constexpr int NBLK = kP * NBT;     // 3120 blocks
constexpr int PASSES = BT / 64;    // 8 (4 waves x 16 rows each per pass)
constexpr int PSTR = 64 * kFD;     // shorts per pass stride (64 rows)

// workspace layout
constexpr size_t X_BF_ELEMS = (size_t)kB * kFD;            // 5,242,880 bf16
constexpr size_t X_BF_BYTES = X_BF_ELEMS * 2;              // 10.49 MB
constexpr size_t W2_VEC_CNT = (size_t)kP * 512;            // bf16x8 vectors
constexpr size_t W2_BYTES   = W2_VEC_CNT * 16;             // 6.39 MB
constexpr size_t WS_NEEDED  = X_BF_BYTES + W2_BYTES;

constexpr int XCONV_BLOCKS = (int)(X_BF_ELEMS / 8 / 256);  // 2560
constexpr int PRE_BLOCKS = XCONV_BLOCKS + kP;              // 3340

__device__ __forceinline__ unsigned short f2bf_bits(float f) {
  unsigned u = __builtin_bit_cast(unsigned, f);
  u += 0x7FFFu + ((u >> 16) & 1u);
  return (unsigned short)(u >> 16);
}
__device__ __forceinline__ float bf2f(unsigned short u) {
  return __builtin_bit_cast(float, (unsigned)u << 16);
}

// ---- pre-pass: convert x -> bf16 (row major) and W -> bf16 fragment-packed
// W2[p][frag=kk*4+nb][lane] as bf16x8, value[t] = W[p][kk*32+hi*8+t][nb*16+lo]
__global__ __launch_bounds__(256) void bilinear_prepass(
    const float* __restrict__ x, const float* __restrict__ W,
    unsigned short* __restrict__ x_bf, ushort8* __restrict__ W2) {
  const int blk = blockIdx.x;
  const int tid = threadIdx.x;
  if (blk < XCONV_BLOCKS) {
    const size_t i = ((size_t)blk * 256 + tid) * 8;
    f32x4 v0 = *(const f32x4*)(x + i);
    f32x4 v1 = *(const f32x4*)(x + i + 4);
    ushort8 o;
#pragma unroll
    for (int t = 0; t < 4; ++t) {
      o[t] = f2bf_bits(v0[t]);
      o[t + 4] = f2bf_bits(v1[t]);
    }
    *(ushort8*)(x_bf + i) = o;
  } else {
    const int p = blk - XCONV_BLOCKS;
    const float* wp = W + (size_t)p * (kD * kD);
#pragma unroll
    for (int rep = 0; rep < 2; ++rep) {
      const int v = tid + rep * 256;       // 512 vectors per p
      const int frag = v >> 6;             // kk*4+nb
      const int lane = v & 63;
      const int kk = frag >> 2, nb = frag & 3;
      const int lo = lane & 15, hi = lane >> 4;
      ushort8 o;
#pragma unroll
      for (int t = 0; t < 8; ++t)
        o[t] = f2bf_bits(wp[(kk * 32 + hi * 8 + t) * kD + nb * 16 + lo]);
      *(ushort8*)&W2[(size_t)p * 512 + v] = o;
    }
  }
}

// ---- main kernel v3: all-bf16 reads + 1-deep software pipeline across passes
__global__ __launch_bounds__(256) void bilinear_main3(
    const unsigned short* __restrict__ x_bf,
    const ushort8* __restrict__ W2, float* __restrict__ out) {
  // btile fixed per XCD -> x_bf slice (2.6 MB) stays L2-resident; p streams.
  const int gid = blockIdx.x;
  const int xcd = gid & 7;
  const int g = gid >> 3;                  // [0, 390)
  const int btile = xcd >> 1;              // [0, 4)  fixed per XCD
  const int p = (xcd & 1) * (kP / 2) + g;  // [0, 780)

  // decode pair (i_f, j_f) from p (triu_indices order, k=1)
  int i_f = 0, s = 0;
  while (s + (kF - 1 - i_f) <= p) { s += kF - 1 - i_f; ++i_f; }
  const int j_f = i_f + 1 + (p - s);

  const int lane = threadIdx.x & 63;
  const int wave = threadIdx.x >> 6;
  const int lo = lane & 15;
  const int hi = lane >> 4;

  // W fragments: 8 coalesced 16B loads, reused over all 8 passes
  bf16x8 bfrag[2][4];
#pragma unroll
  for (int kk = 0; kk < 2; ++kk)
#pragma unroll
    for (int nb = 0; nb < 4; ++nb)
      bfrag[kk][nb] = __builtin_bit_cast(
          bf16x8, W2[(size_t)p * 512 + (kk * 4 + nb) * 64 + lane]);

  const int b0 = btile * BT;
  const size_t rowbase = (size_t)(b0 + wave * 16 + lo) * kFD;
  const unsigned short* xi = x_bf + rowbase + i_f * kD + hi * 8;  // afrag base
  const unsigned short* xj = x_bf + rowbase + j_f * kD + hi * 4;  // xj base

  // prologue: pass-0 loads
  ushort8 aN0 = *(const ushort8*)(xi);
  ushort8 aN1 = *(const ushort8*)(xi + 32);
  u16x4 xN0 = *(const u16x4*)(xj);
  u16x4 xN1 = *(const u16x4*)(xj + 16);
  u16x4 xN2 = *(const u16x4*)(xj + 32);
  u16x4 xN3 = *(const u16x4*)(xj + 48);

#pragma unroll
  for (int pass = 0; pass < PASSES; ++pass) {
    const ushort8 a0 = aN0, a1 = aN1;
    const u16x4 xc0 = xN0, xc1 = xN1, xc2 = xN2, xc3 = xN3;
    if (pass + 1 < PASSES) {               // issue next pass's loads NOW
      const unsigned short* xin = xi + (pass + 1) * PSTR;
      const unsigned short* xjn = xj + (pass + 1) * PSTR;
      aN0 = *(const ushort8*)(xin);
      aN1 = *(const ushort8*)(xin + 32);
      xN0 = *(const u16x4*)(xjn);
      xN1 = *(const u16x4*)(xjn + 16);
      xN2 = *(const u16x4*)(xjn + 32);
      xN3 = *(const u16x4*)(xjn + 48);
    }

    // acc[nb][q] = Y[row][nb*16 + hi*4 + q]
    f32x4 acc[4];
#pragma unroll
    for (int nb = 0; nb < 4; ++nb) acc[nb] = f32x4{0.f, 0.f, 0.f, 0.f};
#pragma unroll
    for (int nb = 0; nb < 4; ++nb)
      acc[nb] = __builtin_amdgcn_mfma_f32_16x16x32_bf16(
          bfrag[0][nb], __builtin_bit_cast(bf16x8, a0), acc[nb], 0, 0, 0);
#pragma unroll
    for (int nb = 0; nb < 4; ++nb)
      acc[nb] = __builtin_amdgcn_mfma_f32_16x16x32_bf16(
          bfrag[1][nb], __builtin_bit_cast(bf16x8, a1), acc[nb], 0, 0, 0);

    // epilogue: 4 independent FMA chains, then combine
    float s0, s1, s2, s3;
    {
      f32x4 v;
      v = f32x4{bf2f(xc0[0]), bf2f(xc0[1]), bf2f(xc0[2]), bf2f(xc0[3])};
      s0 = fmaf(acc[0][3], v[3], fmaf(acc[0][2], v[2],
           fmaf(acc[0][1], v[1], acc[0][0] * v[0])));
      v = f32x4{bf2f(xc1[0]), bf2f(xc1[1]), bf2f(xc1[2]), bf2f(xc1[3])};
      s1 = fmaf(acc[1][3], v[3], fmaf(acc[1][2], v[2],
           fmaf(acc[1][1], v[1], acc[1][0] * v[0])));
      v = f32x4{bf2f(xc2[0]), bf2f(xc2[1]), bf2f(xc2[2]), bf2f(xc2[3])};
      s2 = fmaf(acc[2][3], v[3], fmaf(acc[2][2], v[2],
           fmaf(acc[2][1], v[1], acc[2][0] * v[0])));
      v = f32x4{bf2f(xc3[0]), bf2f(xc3[1]), bf2f(xc3[2]), bf2f(xc3[3])};
      s3 = fmaf(acc[3][3], v[3], fmaf(acc[3][2], v[2],
           fmaf(acc[3][1], v[1], acc[3][0] * v[0])));
    }
    float sum = (s0 + s1) + (s2 + s3);
    sum += __shfl_xor(sum, 16, 64);
    sum += __shfl_xor(sum, 32, 64);
    if (hi == 0)
      out[(size_t)(b0 + pass * 64 + wave * 16 + lo) * kP + p] = sum;
  }
}

// ---- fallback (round-1 kernel) if workspace is too small ----
__global__ __launch_bounds__(256) void bilinear_fb(
    const float* __restrict__ x, const float* __restrict__ W,
    float* __restrict__ out) {
  const int gid = blockIdx.x;
  const int item = (gid & 7) * (NBLK / 8) + (gid >> 3);
  const int p = item >> 2;
  const int btile = item & 3;
  int i_f = 0, s = 0;
  while (s + (kF - 1 - i_f) <= p) { s += kF - 1 - i_f; ++i_f; }
  const int j_f = i_f + 1 + (p - s);
  const int lane = threadIdx.x & 63;
  const int wave = threadIdx.x >> 6;
  const int lo = lane & 15;
  const int hi = lane >> 4;
  const float* wp = W + (size_t)p * (kD * kD);
  bf16x8 bfrag[2][4];
#pragma unroll
  for (int kk = 0; kk < 2; ++kk)
#pragma unroll
    for (int nb = 0; nb < 4; ++nb) {
      ushort8 tmp;
#pragma unroll
      for (int t = 0; t < 8; ++t)
        tmp[t] = f2bf_bits(wp[(kk * 32 + hi * 8 + t) * kD + nb * 16 + lo]);
      bfrag[kk][nb] = __builtin_bit_cast(bf16x8, tmp);
    }
  const int b0 = btile * BT;
  for (int pass = 0; pass < PASSES; ++pass) {
    const int rb = b0 + pass * 64 + wave * 16;
    const float* xi = x + (size_t)(rb + lo) * kFD + i_f * kD;
    bf16x8 afrag[2];
#pragma unroll
    for (int kk = 0; kk < 2; ++kk) {
      f32x4 v0 = *(const f32x4*)(xi + kk * 32 + hi * 8);
      f32x4 v1 = *(const f32x4*)(xi + kk * 32 + hi * 8 + 4);
      ushort8 tmp;
#pragma unroll
      for (int t = 0; t < 4; ++t) {
        tmp[t] = f2bf_bits(v0[t]);
        tmp[t + 4] = f2bf_bits(v1[t]);
      }
      afrag[kk] = __builtin_bit_cast(bf16x8, tmp);
    }
    f32x4 acc[4];
#pragma unroll
    for (int nb = 0; nb < 4; ++nb) acc[nb] = f32x4{0.f, 0.f, 0.f, 0.f};
#pragma unroll
    for (int kk = 0; kk < 2; ++kk)
#pragma unroll
      for (int nb = 0; nb < 4; ++nb)
        acc[nb] = __builtin_amdgcn_mfma_f32_16x16x32_bf16(afrag[kk], bfrag[kk][nb],
                                                          acc[nb], 0, 0, 0);
#pragma unroll
    for (int q = 0; q < 4; ++q) {
      const int row = rb + hi * 4 + q;
      const float* xj = x + (size_t)row * kFD + j_f * kD + lo;
      float sum = 0.f;
#pragma unroll
      for (int nb = 0; nb < 4; ++nb) sum += acc[nb][q] * xj[nb * 16];
      sum += __shfl_xor(sum, 1, 64);
      sum += __shfl_xor(sum, 2, 64);
      sum += __shfl_xor(sum, 4, 64);
      sum += __shfl_xor(sum, 8, 64);
      if (lo == 0) out[(size_t)row * kP + p] = sum;
    }
  }
}

extern "C" void kernel_launch(void* const* d_in, const int* in_sizes, int n_in,
                              void* d_out, int out_size, void* d_ws, size_t ws_size,
                              hipStream_t stream) {
  const float* x = (const float*)d_in[0];
  const float* W = (const float*)d_in[1];
  float* out = (float*)d_out;
  if (ws_size >= WS_NEEDED) {
    unsigned short* x_bf = (unsigned short*)d_ws;
    ushort8* W2 = (ushort8*)((char*)d_ws + X_BF_BYTES);
    hipLaunchKernelGGL(bilinear_prepass, dim3(PRE_BLOCKS), dim3(256), 0, stream,
                       x, W, x_bf, W2);
    hipLaunchKernelGGL(bilinear_main3, dim3(NBLK), dim3(256), 0, stream,
                       x_bf, W2, out);
  } else {
    hipLaunchKernelGGL(bilinear_fb, dim3(NBLK), dim3(256), 0, stream, x, W, out);
  }
}

// Round 8
// 104.399 us; speedup vs baseline: 1.5004x; 1.4705x over previous
//
#include <hip/hip_runtime.h>
#include <hip/hip_bf16.h>

typedef float f32x4 __attribute__((ext_vector_type(4)));
typedef __bf16 bf16x8 __attribute__((ext_vector_type(8)));
typedef unsigned short ushort8 __attribute__((ext_vector_type(8)));
typedef unsigned short u16x4 __attribute__((ext_vector_type(4)));

constexpr int kB = 2048;
constexpr int kF = 40;
constexpr int kD = 64;
constexpr int kP = 780;            // 40*39/2
constexpr int kFD = kF * kD;       // 2560

// workspace layout
constexpr size_t X_BF_ELEMS = (size_t)kB * kFD;            // 5,242,880 bf16
constexpr size_t X_BF_BYTES = X_BF_ELEMS * 2;              // 10.49 MB
constexpr size_t W2_VEC_CNT = (size_t)kP * 512;            // bf16x8 vectors
constexpr size_t W2_BYTES   = W2_VEC_CNT * 16;             // 6.39 MB
constexpr size_t WS_NEEDED  = X_BF_BYTES + W2_BYTES;

constexpr int XCONV_BLOCKS = (int)(X_BF_ELEMS / 8 / 256);  // 2560
constexpr int PRE_BLOCKS = XCONV_BLOCKS + kP;              // 3340

__device__ __forceinline__ unsigned short f2bf_bits(float f) {
  unsigned u = __builtin_bit_cast(unsigned, f);
  u += 0x7FFFu + ((u >> 16) & 1u);
  return (unsigned short)(u >> 16);
}
__device__ __forceinline__ float bf2f(unsigned short u) {
  return __builtin_bit_cast(float, (unsigned)u << 16);
}

// ---- pre-pass: x -> bf16 (coalesced) and W -> bf16 fragment-packed via LDS
// W2[p][frag=kk*4+nb][lane] as ushort8, value[t] = W[p][kk*32+hi*8+t][nb*16+lo]
__global__ __launch_bounds__(256) void bilinear_prepass(
    const float* __restrict__ x, const float* __restrict__ W,
    unsigned short* __restrict__ x_bf, ushort8* __restrict__ W2) {
  __shared__ unsigned short wl[4096];   // one W[p] as bf16 [k][e]
  const int blk = blockIdx.x;
  const int tid = threadIdx.x;
  if (blk < XCONV_BLOCKS) {
    const size_t i = ((size_t)blk * 256 + tid) * 8;
    f32x4 v0 = *(const f32x4*)(x + i);
    f32x4 v1 = *(const f32x4*)(x + i + 4);
    ushort8 o;
#pragma unroll
    for (int t = 0; t < 4; ++t) {
      o[t] = f2bf_bits(v0[t]);
      o[t + 4] = f2bf_bits(v1[t]);
    }
    *(ushort8*)(x_bf + i) = o;
  } else {
    const int p = blk - XCONV_BLOCKS;
    const float* wp = W + (size_t)p * (kD * kD);
    // coalesced load + convert into LDS
#pragma unroll
    for (int k = 0; k < 4; ++k) {
      int i4 = tid + (k << 8);          // float4 index, 1024 total
      f32x4 v = *(const f32x4*)(wp + i4 * 4);
      u16x4 o;
#pragma unroll
      for (int t = 0; t < 4; ++t) o[t] = f2bf_bits(v[t]);
      *(u16x4*)(wl + i4 * 4) = o;
    }
    __syncthreads();
    // permuted gather from LDS, coalesced 16B stores
#pragma unroll
    for (int r = 0; r < 2; ++r) {
      int v = tid + (r << 8);           // dst vector 0..511
      int frag = v >> 6, lane = v & 63;
      int kk = frag >> 2, nb = frag & 3;
      int lo = lane & 15, h2 = lane >> 4;
      ushort8 o;
#pragma unroll
      for (int t = 0; t < 8; ++t)
        o[t] = wl[(kk * 32 + h2 * 8 + t) * 64 + nb * 16 + lo];
      W2[(size_t)p * 512 + v] = o;
    }
  }
}

// ---- main v4 helper: pair loop over staged LDS tile
// af/wc layouts follow the (verified) main2 MFMA mapping:
//   mfma(bfragW, afragX): afrag[t] = x[row=lo][k=kk*32+hi*8+t],
//   bfrag(kk,nb)[t] = W[k=kk*32+hi*8+t][e=nb*16+lo],
//   acc[nb][q] = Y[row=lo][e = nb*16 + hi*4 + q]
template <int NRG, int RSB, int JOFFB, bool CROSS>
__device__ __forceinline__ void pair_loop(
    const unsigned char* smem, const ushort8* __restrict__ W2,
    float* __restrict__ out, int fa, int fb_, int row0,
    int wv, int lo, int hi, int lane) {
  const int NP = CROSS ? 100 : 45;
  int prev_ii = -1;
  ushort8 af[NRG][2];

  int ii, jj;
  {
    int q = wv;
    if constexpr (CROSS) { ii = q / 10; jj = q - ii * 10; }
    else { int s = 0; ii = 0; while (s + 9 - ii <= q) { s += 9 - ii; ++ii; } jj = ii + 1 + (q - s); }
  }
  ushort8 wnx[8];
  {
    int gi = fa + ii, gj = fb_ + jj;
    size_t wb = (size_t)(gi * kF - ((gi * (gi + 1)) >> 1) + gj - gi - 1) * 512;
#pragma unroll
    for (int f = 0; f < 8; ++f) wnx[f] = W2[wb + f * 64 + lane];
  }

  for (int q = wv; q < NP; q += 8) {
    const int cii = ii, cjj = jj;
    ushort8 wc[8];
#pragma unroll
    for (int f = 0; f < 8; ++f) wc[f] = wnx[f];

    int qn = q + 8;
    if (qn < NP) {                       // prefetch next pair's W now
      if constexpr (CROSS) { ii = qn / 10; jj = qn - ii * 10; }
      else { int s = 0; ii = 0; while (s + 9 - ii <= qn) { s += 9 - ii; ++ii; } jj = ii + 1 + (qn - s); }
      int gi = fa + ii, gj = fb_ + jj;
      size_t wb = (size_t)(gi * kF - ((gi * (gi + 1)) >> 1) + gj - gi - 1) * 512;
#pragma unroll
      for (int f = 0; f < 8; ++f) wnx[f] = W2[wb + f * 64 + lane];
    }

    if (cii != prev_ii) {                // afrag cache for all row-groups
      prev_ii = cii;
#pragma unroll
      for (int rg = 0; rg < NRG; ++rg) {
        int row_l = rg * 16 + lo;
        int sw = (row_l & 7) << 4;
#pragma unroll
        for (int kk = 0; kk < 2; ++kk)
          af[rg][kk] = *(const ushort8*)(
              smem + row_l * RSB + ((cii * 128 + kk * 64 + hi * 16) ^ sw));
      }
    }

    const int gi = fa + cii, gj = fb_ + cjj;
    const int p = gi * kF - ((gi * (gi + 1)) >> 1) + gj - gi - 1;

#pragma unroll
    for (int rg = 0; rg < NRG; ++rg) {
      int row_l = rg * 16 + lo;
      int sw = (row_l & 7) << 4;
      u16x4 xj[4];
#pragma unroll
      for (int nb = 0; nb < 4; ++nb)
        xj[nb] = *(const u16x4*)(
            smem + row_l * RSB + ((JOFFB + cjj * 128 + nb * 32 + hi * 8) ^ sw));

      f32x4 acc[4];
#pragma unroll
      for (int nb = 0; nb < 4; ++nb) acc[nb] = f32x4{0.f, 0.f, 0.f, 0.f};
#pragma unroll
      for (int kk = 0; kk < 2; ++kk)
#pragma unroll
        for (int nb = 0; nb < 4; ++nb)
          acc[nb] = __builtin_amdgcn_mfma_f32_16x16x32_bf16(
              __builtin_bit_cast(bf16x8, wc[kk * 4 + nb]),
              __builtin_bit_cast(bf16x8, af[rg][kk]), acc[nb], 0, 0, 0);

      float sm[4];
#pragma unroll
      for (int nb = 0; nb < 4; ++nb)
        sm[nb] = fmaf(acc[nb][3], bf2f(xj[nb][3]),
                 fmaf(acc[nb][2], bf2f(xj[nb][2]),
                 fmaf(acc[nb][1], bf2f(xj[nb][1]),
                      acc[nb][0] * bf2f(xj[nb][0]))));
      float sum = (sm[0] + sm[1]) + (sm[2] + sm[3]);
      sum += __shfl_xor(sum, 16, 64);
      sum += __shfl_xor(sum, 32, 64);
      if (hi == 0) out[(size_t)(row0 + row_l) * kP + p] = sum;
    }
  }
}

// ---- main v4: field-quartered LDS tiles, 256 blocks x 512 threads, 160KB LDS
__global__ __launch_bounds__(512) void bilinear_main4(
    const unsigned short* __restrict__ x_bf, const ushort8* __restrict__ W2,
    float* __restrict__ out) {
  __shared__ __align__(16) unsigned char smem[163840];
  const int gid = blockIdx.x;
  const int item = ((gid & 7) << 5) + (gid >> 3);  // XCD-chunked: XCD k owns [32k,32k+32)
  const int tid = threadIdx.x;
  const int lane = tid & 63;
  const int wv = tid >> 6;
  const int lo = lane & 15;
  const int hi = lane >> 4;

  if (item < 192) {
    // cross class: stage 64 rows x 20 fields (quarters a,b)
    const int cls = item >> 5;
    const int tile = item & 31;
    int a, b;
    if (cls < 3)      { a = 0; b = cls + 1; }
    else if (cls < 5) { a = 1; b = cls - 1; }
    else              { a = 2; b = 3; }
    const int fa = a * 10, fb_ = b * 10;
    const int row0 = tile * 64;
#pragma unroll
    for (int k = 0; k < 20; ++k) {
      int c = tid + (k << 9);
      int rowc = c / 160;
      int rem = c - rowc * 160;
      int half = rem >= 80;
      int off16 = half ? rem - 80 : rem;
      const unsigned short* src = x_bf + (size_t)(row0 + rowc) * kFD
                                  + (half ? fb_ : fa) * 64 + off16 * 8;
      ushort8 v = *(const ushort8*)src;
      int dst = rowc * 2560 + ((half * 1280 + off16 * 16) ^ ((rowc & 7) << 4));
      *(ushort8*)(smem + dst) = v;
    }
    __syncthreads();
    pair_loop<4, 2560, 1280, true>(smem, W2, out, fa, fb_, row0, wv, lo, hi, lane);
  } else {
    // diag class: stage 128 rows x 10 fields
    const int d = (item - 192) >> 4;
    const int tile = (item - 192) & 15;
    const int fa = d * 10;
    const int row0 = tile * 128;
#pragma unroll
    for (int k = 0; k < 20; ++k) {
      int c = tid + (k << 9);
      int rowc = c / 80;
      int off16 = c - rowc * 80;
      const unsigned short* src = x_bf + (size_t)(row0 + rowc) * kFD + fa * 64 + off16 * 8;
      ushort8 v = *(const ushort8*)src;
      *(ushort8*)(smem + rowc * 1280 + ((off16 * 16) ^ ((rowc & 7) << 4))) = v;
    }
    __syncthreads();
    pair_loop<8, 1280, 0, false>(smem, W2, out, fa, fa, row0, wv, lo, hi, lane);
  }
}

// ---- fallback (round-1 kernel) if workspace is too small ----
__global__ __launch_bounds__(256) void bilinear_fb(
    const float* __restrict__ x, const float* __restrict__ W,
    float* __restrict__ out) {
  const int gid = blockIdx.x;
  const int item = (gid & 7) * 390 + (gid >> 3);
  const int p = item >> 2;
  const int btile = item & 3;
  int i_f = 0, s = 0;
  while (s + (kF - 1 - i_f) <= p) { s += kF - 1 - i_f; ++i_f; }
  const int j_f = i_f + 1 + (p - s);
  const int lane = threadIdx.x & 63;
  const int wave = threadIdx.x >> 6;
  const int lo = lane & 15;
  const int hi = lane >> 4;
  const float* wp = W + (size_t)p * (kD * kD);
  bf16x8 bfrag[2][4];
#pragma unroll
  for (int kk = 0; kk < 2; ++kk)
#pragma unroll
    for (int nb = 0; nb < 4; ++nb) {
      ushort8 tmp;
#pragma unroll
      for (int t = 0; t < 8; ++t)
        tmp[t] = f2bf_bits(wp[(kk * 32 + hi * 8 + t) * kD + nb * 16 + lo]);
      bfrag[kk][nb] = __builtin_bit_cast(bf16x8, tmp);
    }
  const int b0 = btile * 512;
  for (int pass = 0; pass < 8; ++pass) {
    const int rb = b0 + pass * 64 + wave * 16;
    const float* xi = x + (size_t)(rb + lo) * kFD + i_f * kD;
    bf16x8 afrag[2];
#pragma unroll
    for (int kk = 0; kk < 2; ++kk) {
      f32x4 v0 = *(const f32x4*)(xi + kk * 32 + hi * 8);
      f32x4 v1 = *(const f32x4*)(xi + kk * 32 + hi * 8 + 4);
      ushort8 tmp;
#pragma unroll
      for (int t = 0; t < 4; ++t) {
        tmp[t] = f2bf_bits(v0[t]);
        tmp[t + 4] = f2bf_bits(v1[t]);
      }
      afrag[kk] = __builtin_bit_cast(bf16x8, tmp);
    }
    f32x4 acc[4];
#pragma unroll
    for (int nb = 0; nb < 4; ++nb) acc[nb] = f32x4{0.f, 0.f, 0.f, 0.f};
#pragma unroll
    for (int kk = 0; kk < 2; ++kk)
#pragma unroll
      for (int nb = 0; nb < 4; ++nb)
        acc[nb] = __builtin_amdgcn_mfma_f32_16x16x32_bf16(afrag[kk], bfrag[kk][nb],
                                                          acc[nb], 0, 0, 0);
#pragma unroll
    for (int q = 0; q < 4; ++q) {
      const int row = rb + hi * 4 + q;
      const float* xj = x + (size_t)row * kFD + j_f * kD + lo;
      float sum = 0.f;
#pragma unroll
      for (int nb = 0; nb < 4; ++nb) sum += acc[nb][q] * xj[nb * 16];
      sum += __shfl_xor(sum, 1, 64);
      sum += __shfl_xor(sum, 2, 64);
      sum += __shfl_xor(sum, 4, 64);
      sum += __shfl_xor(sum, 8, 64);
      if (lo == 0) out[(size_t)row * kP + p] = sum;
    }
  }
}

extern "C" void kernel_launch(void* const* d_in, const int* in_sizes, int n_in,
                              void* d_out, int out_size, void* d_ws, size_t ws_size,
                              hipStream_t stream) {
  const float* x = (const float*)d_in[0];
  const float* W = (const float*)d_in[1];
  float* out = (float*)d_out;
  if (ws_size >= WS_NEEDED) {
    unsigned short* x_bf = (unsigned short*)d_ws;
    ushort8* W2 = (ushort8*)((char*)d_ws + X_BF_BYTES);
    hipLaunchKernelGGL(bilinear_prepass, dim3(PRE_BLOCKS), dim3(256), 0, stream,
                       x, W, x_bf, W2);
    hipLaunchKernelGGL(bilinear_main4, dim3(256), dim3(512), 0, stream,
                       x_bf, W2, out);
  } else {
    hipLaunchKernelGGL(bilinear_fb, dim3(3120), dim3(256), 0, stream, x, W, out);
  }
}